// Round 1
// baseline (13653.265 us; speedup 1.0000x reference)
//
#include <hip/hip_runtime.h>
#include <math.h>

// GATv2 3-layer forward, MI355X. R0: correctness-first atomic scatter version.
// N=100000, E=800000 (+N self loops), Fin=64, H=4, C=16/16/32.

#define HEADS 4
#define NSLOPE 0.2f

__device__ __forceinline__ unsigned enc_f(float f) {
  unsigned u = __float_as_uint(f);
  return (u & 0x80000000u) ? ~u : (u | 0x80000000u);
}
__device__ __forceinline__ float dec_f(unsigned u) {
  unsigned b = (u & 0x80000000u) ? (u & 0x7fffffffu) : ~u;
  return __uint_as_float(b);
}

// xl = in @ Wl, xr = in @ Wr.  in: [N,64], W: [64,COLS], out: [N,COLS].
// One wave per row; W staged in LDS; 64 rows per block.
template <int COLS>
__global__ __launch_bounds__(256) void gemm2_kernel(
    const float* __restrict__ in, const float* __restrict__ Wl,
    const float* __restrict__ Wr, float* __restrict__ xl,
    float* __restrict__ xr, int N) {
  __shared__ float wls[64 * COLS];
  __shared__ float wrs[64 * COLS];
  for (int i = threadIdx.x; i < 64 * COLS; i += 256) {
    wls[i] = Wl[i];
    wrs[i] = Wr[i];
  }
  __syncthreads();
  const int wave = threadIdx.x >> 6;
  const int lane = threadIdx.x & 63;
  const int row0 = blockIdx.x * 64;
  for (int r = wave; r < 64; r += 4) {
    const int row = row0 + r;
    if (row >= N) return;  // rows increase with r; all later iterations OOB too
    const float xv = in[(size_t)row * 64 + lane];
    if (COLS == 64) {
      float al = 0.f, ar = 0.f;
#pragma unroll
      for (int k = 0; k < 64; k++) {
        const float xk = __shfl(xv, k);
        al = fmaf(xk, wls[k * COLS + lane], al);
        ar = fmaf(xk, wrs[k * COLS + lane], ar);
      }
      xl[(size_t)row * COLS + lane] = al;
      xr[(size_t)row * COLS + lane] = ar;
    } else {
      float al0 = 0.f, al1 = 0.f, ar0 = 0.f, ar1 = 0.f;
#pragma unroll
      for (int k = 0; k < 64; k++) {
        const float xk = __shfl(xv, k);
        al0 = fmaf(xk, wls[k * COLS + lane], al0);
        al1 = fmaf(xk, wls[k * COLS + 64 + lane], al1);
        ar0 = fmaf(xk, wrs[k * COLS + lane], ar0);
        ar1 = fmaf(xk, wrs[k * COLS + 64 + lane], ar1);
      }
      xl[(size_t)row * COLS + lane] = al0;
      xl[(size_t)row * COLS + 64 + lane] = al1;
      xr[(size_t)row * COLS + lane] = ar0;
      xr[(size_t)row * COLS + 64 + lane] = ar1;
    }
  }
}

// Per-(edge,head) attention logit + segment-max via encoded atomicMax.
template <int C>
__global__ __launch_bounds__(256) void score_kernel(
    const float* __restrict__ xl, const float* __restrict__ xr,
    const float* __restrict__ att, const int* __restrict__ ei, int E, int ET,
    float* __restrict__ sbuf, unsigned* __restrict__ menc) {
  const int t = blockIdx.x * 256 + threadIdx.x;
  if (t >= ET * HEADS) return;
  const int e = t >> 2, h = t & 3;
  int s, d;
  if (e < E) {
    s = ei[e];
    d = ei[E + e];
  } else {
    s = e - E;
    d = s;
  }
  const float4* ap = (const float4*)(xl + ((size_t)s * HEADS + h) * C);
  const float4* bp = (const float4*)(xr + ((size_t)d * HEADS + h) * C);
  const float4* wp = (const float4*)(att + h * C);
  float acc = 0.f;
#pragma unroll
  for (int c = 0; c < C / 4; c++) {
    const float4 a = ap[c], b = bp[c], w = wp[c];
    float v;
    v = a.x + b.x; v = v > 0.f ? v : v * NSLOPE; acc = fmaf(v, w.x, acc);
    v = a.y + b.y; v = v > 0.f ? v : v * NSLOPE; acc = fmaf(v, w.y, acc);
    v = a.z + b.z; v = v > 0.f ? v : v * NSLOPE; acc = fmaf(v, w.z, acc);
    v = a.w + b.w; v = v > 0.f ? v : v * NSLOPE; acc = fmaf(v, w.w, acc);
  }
  sbuf[t] = acc;
  atomicMax(menc + (size_t)d * HEADS + h, enc_f(acc));
}

// exp(s-m); accumulate denom and ex*xl[src] into acc via fp32 atomics.
template <int C>
__global__ __launch_bounds__(256) void agg_kernel(
    const float* __restrict__ xl, const float* __restrict__ sbuf,
    const unsigned* __restrict__ menc, const int* __restrict__ ei, int E,
    int ET, float* __restrict__ denom, float* __restrict__ acc) {
  const int t = blockIdx.x * 256 + threadIdx.x;
  if (t >= ET * HEADS) return;
  const int e = t >> 2, h = t & 3;
  int s, d;
  if (e < E) {
    s = ei[e];
    d = ei[E + e];
  } else {
    s = e - E;
    d = s;
  }
  const float sc = sbuf[t];
  const float m = dec_f(menc[(size_t)d * HEADS + h]);
  const float ex = __expf(sc - m);
  unsafeAtomicAdd(denom + (size_t)d * HEADS + h, ex);
  const float4* ap = (const float4*)(xl + ((size_t)s * HEADS + h) * C);
  float* op = acc + ((size_t)d * HEADS + h) * C;
#pragma unroll
  for (int c = 0; c < C / 4; c++) {
    const float4 a = ap[c];
    unsafeAtomicAdd(op + 4 * c + 0, ex * a.x);
    unsafeAtomicAdd(op + 4 * c + 1, ex * a.y);
    unsafeAtomicAdd(op + 4 * c + 2, ex * a.z);
    unsafeAtomicAdd(op + 4 * c + 3, ex * a.w);
  }
}

// Layers 1-2: out = elu(acc/denom + bias), concat layout [N,64].
__global__ __launch_bounds__(256) void finalize_cat_kernel(
    const float* __restrict__ acc, const float* __restrict__ denom,
    const float* __restrict__ bias, float* __restrict__ out, int N) {
  const int t = blockIdx.x * 256 + threadIdx.x;
  if (t >= N * 64) return;
  const int n = t >> 6, j = t & 63;
  const float v = acc[t] / denom[(size_t)n * HEADS + (j >> 4)] + bias[j];
  out[t] = v > 0.f ? v : (__expf(v) - 1.f);
}

// Layer 3: out = mean_h(acc/denom) + bias, [N,32], no activation.
__global__ __launch_bounds__(256) void finalize_mean_kernel(
    const float* __restrict__ acc, const float* __restrict__ denom,
    const float* __restrict__ bias, float* __restrict__ out, int N) {
  const int t = blockIdx.x * 256 + threadIdx.x;
  if (t >= N * 32) return;
  const int n = t >> 5, c = t & 31;
  float v = 0.f;
#pragma unroll
  for (int h = 0; h < HEADS; h++)
    v += acc[((size_t)n * HEADS + h) * 32 + c] / denom[(size_t)n * HEADS + h];
  out[t] = v * 0.25f + bias[c];
}

extern "C" void kernel_launch(void* const* d_in, const int* in_sizes, int n_in,
                              void* d_out, int out_size, void* d_ws,
                              size_t ws_size, hipStream_t stream) {
  const float* x = (const float*)d_in[0];
  const int* ei = (const int*)d_in[1];
  const float* W1l = (const float*)d_in[2];
  const float* W1r = (const float*)d_in[3];
  const float* a1 = (const float*)d_in[4];
  const float* b1 = (const float*)d_in[5];
  const float* W2l = (const float*)d_in[6];
  const float* W2r = (const float*)d_in[7];
  const float* a2 = (const float*)d_in[8];
  const float* b2 = (const float*)d_in[9];
  const float* W3l = (const float*)d_in[10];
  const float* W3r = (const float*)d_in[11];
  const float* a3 = (const float*)d_in[12];
  const float* b3 = (const float*)d_in[13];

  const int N = in_sizes[0] / 64;
  const int E = in_sizes[1] / 2;
  const int ET = E + N;

  char* ws = (char*)d_ws;
  const size_t szBig = (size_t)N * 128 * sizeof(float);  // 51.2 MB
  const size_t szH = (size_t)N * 64 * sizeof(float);     // 25.6 MB
  const size_t szS = (size_t)ET * HEADS * sizeof(float); // 14.4 MB
  const size_t szM = (size_t)N * HEADS * sizeof(float);  // 1.6 MB
  float* xl = (float*)(ws);
  float* xr = (float*)(ws + szBig);  // also re-used as acc (see memset below)
  float* h1 = (float*)(ws + 2 * szBig);
  float* h2 = (float*)(ws + 2 * szBig + szH);
  float* sbuf = (float*)(ws + 2 * szBig + 2 * szH);
  unsigned* menc = (unsigned*)(ws + 2 * szBig + 2 * szH + szS);
  float* denom = (float*)(ws + 2 * szBig + 2 * szH + szS + szM);

  const int gemmBlocks = (N + 63) / 64;
  const int edgeThreads = ET * HEADS;
  const int edgeBlocks = (edgeThreads + 255) / 256;

  auto layer = [&](const float* in, const float* Wl, const float* Wr,
                   const float* att, const float* bias, int C, float* out,
                   bool final_mean) {
    // m encoded so that 0x00000000 < enc(any float); every node has a
    // self-loop so every (dst,h) slot is written before being read.
    hipMemsetAsync(menc, 0, szM, stream);
    hipMemsetAsync(denom, 0, szM, stream);
    if (C == 16) {
      gemm2_kernel<64><<<gemmBlocks, 256, 0, stream>>>(in, Wl, Wr, xl, xr, N);
      score_kernel<16><<<edgeBlocks, 256, 0, stream>>>(xl, xr, att, ei, E, ET,
                                                       sbuf, menc);
      hipMemsetAsync(xr, 0, (size_t)N * HEADS * 16 * sizeof(float), stream);
      agg_kernel<16><<<edgeBlocks, 256, 0, stream>>>(xl, sbuf, menc, ei, E, ET,
                                                     denom, xr);
    } else {
      gemm2_kernel<128><<<gemmBlocks, 256, 0, stream>>>(in, Wl, Wr, xl, xr, N);
      score_kernel<32><<<edgeBlocks, 256, 0, stream>>>(xl, xr, att, ei, E, ET,
                                                       sbuf, menc);
      hipMemsetAsync(xr, 0, (size_t)N * HEADS * 32 * sizeof(float), stream);
      agg_kernel<32><<<edgeBlocks, 256, 0, stream>>>(xl, sbuf, menc, ei, E, ET,
                                                     denom, xr);
    }
    if (!final_mean) {
      finalize_cat_kernel<<<(N * 64 + 255) / 256, 256, 0, stream>>>(
          xr, denom, bias, out, N);
    } else {
      finalize_mean_kernel<<<(N * 32 + 255) / 256, 256, 0, stream>>>(
          xr, denom, bias, out, N);
    }
  };

  layer(x, W1l, W1r, a1, b1, 16, h1, false);
  layer(h1, W2l, W2r, a2, b2, 16, h2, false);
  layer(h2, W3l, W3r, a3, b3, 32, (float*)d_out, true);
}

// Round 2
// 934.951 us; speedup vs baseline: 14.6032x; 14.6032x over previous
//
#include <hip/hip_runtime.h>
#include <math.h>

// GATv2 3-layer forward, MI355X.
// R1: CSR-by-dst (built once, reused 3 layers) + fused flash-style per-node
// online-softmax gather. Zero fp32 scatter atomics (R0's 6ms/layer bottleneck:
// 3.6 GB atomic writeback traffic per agg dispatch).
// N=100000, E=800000 (+N self loops), Fin=64, H=4, C=16/16/32.

#define HEADS 4
#define NSLOPE 0.2f

// ---------------------------------------------------------------------------
// xl = in @ Wl, xr = in @ Wr.  in: [N,64], W: [64,COLS], out: [N,COLS].
// One wave per row; W staged in LDS; 64 rows per block.
template <int COLS>
__global__ __launch_bounds__(256) void gemm2_kernel(
    const float* __restrict__ in, const float* __restrict__ Wl,
    const float* __restrict__ Wr, float* __restrict__ xl,
    float* __restrict__ xr, int N) {
  __shared__ float wls[64 * COLS];
  __shared__ float wrs[64 * COLS];
  for (int i = threadIdx.x; i < 64 * COLS; i += 256) {
    wls[i] = Wl[i];
    wrs[i] = Wr[i];
  }
  __syncthreads();
  const int wave = threadIdx.x >> 6;
  const int lane = threadIdx.x & 63;
  const int row0 = blockIdx.x * 64;
  for (int r = wave; r < 64; r += 4) {
    const int row = row0 + r;
    if (row >= N) return;  // rows increase with r; later iterations OOB too
    const float xv = in[(size_t)row * 64 + lane];
    if (COLS == 64) {
      float al = 0.f, ar = 0.f;
#pragma unroll
      for (int k = 0; k < 64; k++) {
        const float xk = __shfl(xv, k);
        al = fmaf(xk, wls[k * COLS + lane], al);
        ar = fmaf(xk, wrs[k * COLS + lane], ar);
      }
      xl[(size_t)row * COLS + lane] = al;
      xr[(size_t)row * COLS + lane] = ar;
    } else {
      float al0 = 0.f, al1 = 0.f, ar0 = 0.f, ar1 = 0.f;
#pragma unroll
      for (int k = 0; k < 64; k++) {
        const float xk = __shfl(xv, k);
        al0 = fmaf(xk, wls[k * COLS + lane], al0);
        al1 = fmaf(xk, wls[k * COLS + 64 + lane], al1);
        ar0 = fmaf(xk, wrs[k * COLS + lane], ar0);
        ar1 = fmaf(xk, wrs[k * COLS + 64 + lane], ar1);
      }
      xl[(size_t)row * COLS + lane] = al0;
      xl[(size_t)row * COLS + 64 + lane] = al1;
      xr[(size_t)row * COLS + lane] = ar0;
      xr[(size_t)row * COLS + 64 + lane] = ar1;
    }
  }
}

// ---------------------------------------------------------------------------
// CSR build: deg count -> exclusive scan -> cursor fill.
__global__ __launch_bounds__(256) void count_kernel(const int* __restrict__ ei,
                                                    int E, int ET,
                                                    int* __restrict__ deg) {
  const int e = blockIdx.x * 256 + threadIdx.x;
  if (e >= ET) return;
  const int d = (e < E) ? ei[E + e] : (e - E);
  atomicAdd(deg + d, 1);
}

// Single-block hierarchical exclusive scan of deg[0..N) -> row_ofs[0..N].
__global__ __launch_bounds__(1024) void scan_kernel(const int* __restrict__ deg,
                                                    int* __restrict__ row_ofs,
                                                    int N) {
  __shared__ int wsums[16];
  __shared__ int s_carry;
  if (threadIdx.x == 0) s_carry = 0;
  const int lane = threadIdx.x & 63;
  const int wave = threadIdx.x >> 6;
  __syncthreads();
  for (int base = 0; base < N; base += 1024) {
    const int i = base + threadIdx.x;
    const int v = (i < N) ? deg[i] : 0;
    int x = v;  // wave-level inclusive scan
#pragma unroll
    for (int off = 1; off < 64; off <<= 1) {
      const int y = __shfl_up(x, off);
      if (lane >= off) x += y;
    }
    if (lane == 63) wsums[wave] = x;
    __syncthreads();
    if (threadIdx.x < 16) {
      int w = wsums[threadIdx.x];
#pragma unroll
      for (int off = 1; off < 16; off <<= 1) {
        const int y = __shfl_up(w, off);
        if ((int)threadIdx.x >= off) w += y;
      }
      wsums[threadIdx.x] = w;  // inclusive scan of wave sums
    }
    __syncthreads();
    const int wbase = wave ? wsums[wave - 1] : 0;
    if (i < N) row_ofs[i] = s_carry + wbase + (x - v);
    const int total = wsums[15];
    __syncthreads();
    if (threadIdx.x == 0) s_carry += total;
    __syncthreads();
  }
  if (threadIdx.x == 0) row_ofs[N] = s_carry;
}

__global__ __launch_bounds__(256) void copy_kernel(const int* __restrict__ src,
                                                   int* __restrict__ dst,
                                                   int n) {
  const int i = blockIdx.x * 256 + threadIdx.x;
  if (i < n) dst[i] = src[i];
}

__global__ __launch_bounds__(256) void fill_kernel(const int* __restrict__ ei,
                                                   int E, int ET,
                                                   int* __restrict__ cursor,
                                                   int* __restrict__ csr_src) {
  const int e = blockIdx.x * 256 + threadIdx.x;
  if (e >= ET) return;
  int s, d;
  if (e < E) {
    s = ei[e];
    d = ei[E + e];
  } else {
    s = d = e - E;
  }
  const int pos = atomicAdd(cursor + d, 1);
  csr_src[pos] = s;
}

// ---------------------------------------------------------------------------
// Fused per-(node,head) online-softmax aggregation.
// MODE 0: out[n*H*C + h*C + c] = elu(agg + bias)   (concat layers)
// MODE 1: out[n*C + c] = mean_h(agg) + bias        (final layer, shfl over 4
//         adjacent head-lanes; each lane then writes its C/4-channel slice)
template <int C, int MODE>
__global__ __launch_bounds__(256) void node_agg_kernel(
    const float* __restrict__ xl, const float* __restrict__ xr,
    const float* __restrict__ att, const float* __restrict__ bias,
    const int* __restrict__ row_ofs, const int* __restrict__ csr_src,
    float* __restrict__ out, int N) {
  const int t = blockIdx.x * 256 + threadIdx.x;
  if (t >= N * HEADS) return;
  const int n = t >> 2, h = t & 3;
  float xr_r[C], att_r[C], acc[C];
  const float4* xrp = (const float4*)(xr + ((size_t)n * HEADS + h) * C);
  const float4* atp = (const float4*)(att + h * C);
#pragma unroll
  for (int c = 0; c < C / 4; c++) {
    ((float4*)xr_r)[c] = xrp[c];
    ((float4*)att_r)[c] = atp[c];
  }
#pragma unroll
  for (int c = 0; c < C; c++) acc[c] = 0.f;
  float m = -1e30f, l = 0.f;
  const int jb = row_ofs[n], je = row_ofs[n + 1];
  for (int j = jb; j < je; j++) {
    const int s = csr_src[j];
    float xs[C];
    const float4* xp = (const float4*)(xl + ((size_t)s * HEADS + h) * C);
#pragma unroll
    for (int c = 0; c < C / 4; c++) ((float4*)xs)[c] = xp[c];
    float sc = 0.f;
#pragma unroll
    for (int c = 0; c < C; c++) {
      float v = xs[c] + xr_r[c];
      v = v > 0.f ? v : v * NSLOPE;
      sc = fmaf(v, att_r[c], sc);
    }
    const float nm = fmaxf(m, sc);
    const float scale = __expf(m - nm);
    const float e = __expf(sc - nm);
    m = nm;
    l = fmaf(l, scale, e);
#pragma unroll
    for (int c = 0; c < C; c++) acc[c] = fmaf(acc[c], scale, e * xs[c]);
  }
  const float inv = 1.f / l;
  if (MODE == 0) {
    float ob[C];
#pragma unroll
    for (int c = 0; c < C; c++) {
      const float v = fmaf(acc[c], inv, bias[h * C + c]);
      ob[c] = v > 0.f ? v : (__expf(v) - 1.f);
    }
    float4* op = (float4*)(out + ((size_t)n * HEADS + h) * C);
#pragma unroll
    for (int c = 0; c < C / 4; c++) op[c] = ((float4*)ob)[c];
  } else {
    // butterfly head-sum over the 4 adjacent lanes (all lanes get the sum);
    // whole 4-lane groups are alive together since N*HEADS % 4 == 0.
#pragma unroll
    for (int c = 0; c < C; c++) {
      float v = acc[c] * inv;
      v += __shfl_xor(v, 1);
      v += __shfl_xor(v, 2);
      acc[c] = v * 0.25f;
    }
    const int c0 = h * (C / 4);  // this lane's slice of the mean vector
    float ob[C / 4];
#pragma unroll
    for (int c = 0; c < C / 4; c++) ob[c] = acc[c0 + c] + bias[c0 + c];
    float4* op = (float4*)(out + (size_t)n * C + c0);
#pragma unroll
    for (int c = 0; c < C / 16; c++) op[c] = ((float4*)ob)[c];
  }
}

// ---------------------------------------------------------------------------
extern "C" void kernel_launch(void* const* d_in, const int* in_sizes, int n_in,
                              void* d_out, int out_size, void* d_ws,
                              size_t ws_size, hipStream_t stream) {
  const float* x = (const float*)d_in[0];
  const int* ei = (const int*)d_in[1];
  const float* W1l = (const float*)d_in[2];
  const float* W1r = (const float*)d_in[3];
  const float* a1 = (const float*)d_in[4];
  const float* b1 = (const float*)d_in[5];
  const float* W2l = (const float*)d_in[6];
  const float* W2r = (const float*)d_in[7];
  const float* a2 = (const float*)d_in[8];
  const float* b2 = (const float*)d_in[9];
  const float* W3l = (const float*)d_in[10];
  const float* W3r = (const float*)d_in[11];
  const float* a3 = (const float*)d_in[12];
  const float* b3 = (const float*)d_in[13];

  const int N = in_sizes[0] / 64;
  const int E = in_sizes[1] / 2;
  const int ET = E + N;

  char* ws = (char*)d_ws;
  const size_t szBig = (size_t)N * 128 * sizeof(float);  // 51.2 MB
  const size_t szH = (size_t)N * 64 * sizeof(float);     // 25.6 MB
  float* xl = (float*)(ws);
  float* xr = (float*)(ws + szBig);
  float* h1 = (float*)(ws + 2 * szBig);
  float* h2 = (float*)(ws + 2 * szBig + szH);
  char* p = ws + 2 * szBig + 2 * szH;
  int* deg = (int*)p;                                  p += (size_t)N * 4;
  int* row_ofs = (int*)p;                              p += (size_t)(N + 1) * 4;
  int* cursor = (int*)p;                               p += (size_t)N * 4;
  int* csr_src = (int*)p;

  const int gemmBlocks = (N + 63) / 64;
  const int edgeBlocks = (ET + 255) / 256;
  const int nodeBlocks = (N + 255) / 256;
  const int nhBlocks = (N * HEADS + 255) / 256;

  // ---- CSR build (graph identical for all 3 layers) ----
  hipMemsetAsync(deg, 0, (size_t)N * 4, stream);
  count_kernel<<<edgeBlocks, 256, 0, stream>>>(ei, E, ET, deg);
  scan_kernel<<<1, 1024, 0, stream>>>(deg, row_ofs, N);
  copy_kernel<<<nodeBlocks, 256, 0, stream>>>(row_ofs, cursor, N);
  fill_kernel<<<edgeBlocks, 256, 0, stream>>>(ei, E, ET, cursor, csr_src);

  // ---- Layer 1: 64 -> 4x16, concat, ELU ----
  gemm2_kernel<64><<<gemmBlocks, 256, 0, stream>>>(x, W1l, W1r, xl, xr, N);
  node_agg_kernel<16, 0><<<nhBlocks, 256, 0, stream>>>(xl, xr, a1, b1, row_ofs,
                                                       csr_src, h1, N);
  // ---- Layer 2: 64 -> 4x16, concat, ELU ----
  gemm2_kernel<64><<<gemmBlocks, 256, 0, stream>>>(h1, W2l, W2r, xl, xr, N);
  node_agg_kernel<16, 0><<<nhBlocks, 256, 0, stream>>>(xl, xr, a2, b2, row_ofs,
                                                       csr_src, h2, N);
  // ---- Layer 3: 64 -> 4x32, mean over heads ----
  gemm2_kernel<128><<<gemmBlocks, 256, 0, stream>>>(h2, W3l, W3r, xl, xr, N);
  node_agg_kernel<32, 1><<<nhBlocks, 256, 0, stream>>>(
      xl, xr, a3, b3, row_ofs, csr_src, (float*)d_out, N);
}